// Round 3
// baseline (337.035 us; speedup 1.0000x reference)
//
#include <hip/hip_runtime.h>
#include <hip/hip_fp16.h>
#include <math.h>

typedef _Float16 f16;
typedef _Float16 f16x8 __attribute__((ext_vector_type(8)));
typedef _Float16 f16x4 __attribute__((ext_vector_type(4)));
typedef float    f32x4 __attribute__((ext_vector_type(4)));

#define MFMA16(a,b,c) __builtin_amdgcn_mfma_f32_16x16x32_f16(a, b, c, 0, 0, 0)

// log2-domain masked-fill sentinel; exp2(MASKNEG - m_real) underflows to 0,
// and a row whose max stays MASKNEG is "fully masked" -> uniform-softmax
// override in the epilogue (exactly matching the reference's finite -2^32 fill).
#define MASKNEG (-6.0e9f)
#define LOG2E   1.44269504088896f

// ---------------------------------------------------------------------------
// Kernel 1: QKV projection.  out[m,c] = sum_k x[m,k] * W[c,k] + b[c]
// x: [8192,512] f32.  Q,K written natural f16 [8192][512]; V written
// transposed f16 [(h*4+b)*64+d][2048] for the attention PV step.
// Tile 128x64, 4 waves (2x2), BK=32 (one f16 MFMA K-step).
// ---------------------------------------------------------------------------
__global__ __launch_bounds__(256) void qkv_gemm(
    const float* __restrict__ x,
    const float* __restrict__ Wq, const float* __restrict__ bq,
    const float* __restrict__ Wk, const float* __restrict__ bk,
    const float* __restrict__ Wv, const float* __restrict__ bv,
    f16* __restrict__ Qws, f16* __restrict__ Kws, f16* __restrict__ Vt)
{
    __shared__ f16 Al[128 * 48];   // stride 48 f16 = 96B (16B aligned rows)
    __shared__ f16 Wl[64 * 48];

    const int tid = threadIdx.x;
    const int bx  = blockIdx.x;          // 0..23 (3 weights x 8 n-tiles)
    const int m0  = blockIdx.y * 128;
    const int widx = bx >> 3;            // 0=Q 1=K 2=V
    const int n0   = (bx & 7) * 64;

    const float* W    = (widx == 0) ? Wq : (widx == 1) ? Wk : Wv;
    const float* bias = (widx == 0) ? bq : (widx == 1) ? bk : bv;

    const int wid = tid >> 6, lane = tid & 63;
    const int g = lane >> 4, c = lane & 15;
    const int wm = (wid >> 1) * 64, wn = (wid & 1) * 32;

    const int sr = tid >> 3, sc = tid & 7;   // staging: 32 rows x 8 float4-chunks

    f32x4 acc[4][2] = {};

    for (int kk = 0; kk < 512; kk += 32) {
        __syncthreads();
        #pragma unroll
        for (int rr = 0; rr < 4; ++rr) {            // A: 128 rows x 32 k
            int row = sr + rr * 32;
            float4 v = *(const float4*)&x[(size_t)(m0 + row) * 512 + kk + sc * 4];
            f16x4 h4 = {(f16)v.x, (f16)v.y, (f16)v.z, (f16)v.w};
            *(f16x4*)&Al[row * 48 + sc * 4] = h4;
        }
        #pragma unroll
        for (int rr = 0; rr < 2; ++rr) {            // W: 64 rows x 32 k
            int row = sr + rr * 32;
            float4 v = *(const float4*)&W[(size_t)(n0 + row) * 512 + kk + sc * 4];
            f16x4 h4 = {(f16)v.x, (f16)v.y, (f16)v.z, (f16)v.w};
            *(f16x4*)&Wl[row * 48 + sc * 4] = h4;
        }
        __syncthreads();

        // B-frag: lane -> W[n=c, k=g*8+j] (natural [n][k] LDS rows)
        f16x8 b0 = *(const f16x8*)&Wl[(wn +  0 + c) * 48 + g * 8];
        f16x8 b1 = *(const f16x8*)&Wl[(wn + 16 + c) * 48 + g * 8];
        #pragma unroll
        for (int mf = 0; mf < 4; ++mf) {
            f16x8 a = *(const f16x8*)&Al[(wm + mf * 16 + c) * 48 + g * 8];
            acc[mf][0] = MFMA16(a, b0, acc[mf][0]);
            acc[mf][1] = MFMA16(a, b1, acc[mf][1]);
        }
    }

    // Epilogue. C/D layout: col = c (lane&15), row = g*4 + reg.
    #pragma unroll
    for (int nf = 0; nf < 2; ++nf) {
        int cc = n0 + wn + nf * 16 + c;      // output channel within this matrix
        float bval = bias[cc];
        #pragma unroll
        for (int mf = 0; mf < 4; ++mf) {
            if (widx < 2) {
                f16* outp = (widx == 0) ? Qws : Kws;
                #pragma unroll
                for (int r = 0; r < 4; ++r) {
                    int mrow = m0 + wm + mf * 16 + g * 4 + r;
                    outp[(size_t)mrow * 512 + cc] = (f16)(acc[mf][nf][r] + bval);
                }
            } else {
                // V transposed: row = n*64+d, col = t  (n = h*4+b)
                int h  = n0 >> 6;
                int d  = wn + nf * 16 + c;
                int t0 = m0 + wm + mf * 16 + g * 4;    // global m, mult of 4
                int b  = t0 >> 11;
                int ts = t0 & 2047;
                int nn = h * 4 + b;
                f16x4 pk = {(f16)(acc[mf][nf][0] + bval), (f16)(acc[mf][nf][1] + bval),
                            (f16)(acc[mf][nf][2] + bval), (f16)(acc[mf][nf][3] + bval)};
                *(f16x4*)&Vt[((size_t)(nn * 64 + d)) * 2048 + ts] = pk;
            }
        }
    }
}

// ---------------------------------------------------------------------------
// Kernel 1b: per-(n,d) sum of V over t, for the fully-masked-row override.
// ---------------------------------------------------------------------------
__global__ __launch_bounds__(256) void vsum_kernel(
    const f16* __restrict__ Vt, float* __restrict__ Vsum)
{
    const int row  = blockIdx.x * 4 + (threadIdx.x >> 6);
    const int lane = threadIdx.x & 63;
    const f16* p = Vt + (size_t)row * 2048;
    float s = 0.f;
    #pragma unroll
    for (int i = 0; i < 4; ++i) {
        f16x8 v = *(const f16x8*)&p[i * 512 + lane * 8];
        #pragma unroll
        for (int j = 0; j < 8; ++j) s += (float)v[j];
    }
    #pragma unroll
    for (int off = 1; off < 64; off <<= 1) s += __shfl_xor(s, off, 64);
    if (lane == 0) Vsum[row] = s;
}

// ---------------------------------------------------------------------------
// Kernel 2: fused attention.  One block = one (n = h*4+b) x 128 q-rows,
// 4 waves x 32 q-rows (mi=0,1 sub-tiles of 16).  Branch-free split k-loop:
//   tiles [0, live): K+V stage, QK^T, pre_score store, mask, online softmax
//                    (log2 domain), P bounce via wave-private LDS, PV MFMA.
//   tiles [live,32): K stage, QK^T, pre_score store only (causally dead:
//                    their softmax contribution is exp2(MASKNEG-m)=0, unless
//                    the row is fully masked -> Vsum/2048 epilogue override).
// live = 2*qt+2 is block-uniform.
// ---------------------------------------------------------------------------
__global__ __launch_bounds__(256) void attn_kernel(
    const f16* __restrict__ Qws, const f16* __restrict__ Kws,
    const f16* __restrict__ Vt,  const int* __restrict__ pmask,
    const float* __restrict__ Vsum,
    float* __restrict__ pre_score, f16* __restrict__ attn_out)
{
    __shared__ f16 Kl[64 * 72];        // [t][d], stride 72 f16 = 144B
    __shared__ f16 Vl[64 * 72];        // [d][t]
    __shared__ f16 Pl[4][32 * 72];     // per-wave [q][t]

    const int tid = threadIdx.x;
    const int wid = tid >> 6, lane = tid & 63;
    const int g = lane >> 4, c = lane & 15;
    const int qt = blockIdx.x;         // 0..15 (128 q-rows each)
    const int n  = blockIdx.y;         // 0..31  (= h*4 + b)
    const int h = n >> 2, b = n & 3;
    const int pmrow = n >> 3;          // the reference's ordering quirk
    const int q0 = qt * 128 + wid * 32;
    const int live = 2 * qt + 2;       // tiles with any causally-valid key

    // Q fragments in registers (A-op: lane -> Q[q=c, k=g*8+j])
    f16x8 qf[2][2];
    #pragma unroll
    for (int mi = 0; mi < 2; ++mi)
        #pragma unroll
        for (int ks = 0; ks < 2; ++ks)
            qf[mi][ks] = *(const f16x8*)
                &Qws[(size_t)(b * 2048 + q0 + mi * 16 + c) * 512 + h * 64 + ks * 32 + g * 8];

    f32x4 o[2][4] = {};
    float mrow[2][4], lrow[2][4];
    #pragma unroll
    for (int mi = 0; mi < 2; ++mi)
        #pragma unroll
        for (int r = 0; r < 4; ++r) { mrow[mi][r] = -INFINITY; lrow[mi][r] = 0.0f; }

    const int sr = tid >> 3, sc = tid & 7;
    const int* pmp = pmask + pmrow * 2048;
    const f16* Kbase = Kws + (size_t)(b * 2048) * 512 + h * 64;
    const f16* Vbase = Vt + (size_t)(n * 64) * 2048;

    // ---------------- live tiles: full flash-attention body ----------------
    for (int kt = 0; kt < live; ++kt) {
        __syncthreads();
        #pragma unroll
        for (int rr = 0; rr < 2; ++rr) {
            int row = sr + rr * 32;
            *(uint4*)&Kl[row * 72 + sc * 8] =
                *(const uint4*)&Kbase[(size_t)(kt * 64 + row) * 512 + sc * 8];
            *(uint4*)&Vl[row * 72 + sc * 8] =
                *(const uint4*)&Vbase[(size_t)row * 2048 + kt * 64 + sc * 8];
        }
        __syncthreads();

        f32x4 s[2][4] = {};
        #pragma unroll
        for (int nf = 0; nf < 4; ++nf)
            #pragma unroll
            for (int ks = 0; ks < 2; ++ks) {
                f16x8 kf = *(const f16x8*)&Kl[(nf * 16 + c) * 72 + ks * 32 + g * 8];
                s[0][nf] = MFMA16(qf[0][ks], kf, s[0][nf]);
                s[1][nf] = MFMA16(qf[1][ks], kf, s[1][nf]);
            }

        // emit pre_score (unmasked, scaled); convert to log2-domain + mask in-place
        #pragma unroll
        for (int nf = 0; nf < 4; ++nf) {
            int tg  = kt * 64 + nf * 16 + c;
            int pmv = pmp[tg];
            #pragma unroll
            for (int mi = 0; mi < 2; ++mi)
                #pragma unroll
                for (int r = 0; r < 4; ++r) {
                    float v = s[mi][nf][r] * 0.125f;
                    int srow = q0 + mi * 16 + g * 4 + r;
                    __builtin_nontemporal_store(
                        v, &pre_score[((size_t)n * 2048 + srow) * 2048 + tg]);
                    s[mi][nf][r] = (tg <= srow && pmv != 0) ? v * LOG2E : MASKNEG;
                }
        }

        // online softmax (log2 domain)
        float alpha[2][4];
        #pragma unroll
        for (int mi = 0; mi < 2; ++mi)
            #pragma unroll
            for (int r = 0; r < 4; ++r) {
                float rm = fmaxf(fmaxf(s[mi][0][r], s[mi][1][r]),
                                 fmaxf(s[mi][2][r], s[mi][3][r]));
                rm = fmaxf(rm, __shfl_xor(rm, 1, 64));
                rm = fmaxf(rm, __shfl_xor(rm, 2, 64));
                rm = fmaxf(rm, __shfl_xor(rm, 4, 64));
                rm = fmaxf(rm, __shfl_xor(rm, 8, 64));
                float mn = fmaxf(mrow[mi][r], rm);
                alpha[mi][r] = exp2f(mrow[mi][r] - mn);   // exp2(-inf)=0 first tile
                mrow[mi][r] = mn;
            }
        #pragma unroll
        for (int mi = 0; mi < 2; ++mi) {
            float rs[4] = {0.f, 0.f, 0.f, 0.f};
            #pragma unroll
            for (int nf = 0; nf < 4; ++nf)
                #pragma unroll
                for (int r = 0; r < 4; ++r) {
                    float p = exp2f(s[mi][nf][r] - mrow[mi][r]);
                    rs[r] += p;
                    Pl[wid][(mi * 16 + g * 4 + r) * 72 + nf * 16 + c] = (f16)p;
                }
            #pragma unroll
            for (int r = 0; r < 4; ++r) {
                float t = rs[r];
                t += __shfl_xor(t, 1, 64);
                t += __shfl_xor(t, 2, 64);
                t += __shfl_xor(t, 4, 64);
                t += __shfl_xor(t, 8, 64);
                lrow[mi][r] = lrow[mi][r] * alpha[mi][r] + t;
                #pragma unroll
                for (int dn = 0; dn < 4; ++dn) o[mi][dn][r] *= alpha[mi][r];
            }
        }
        // Pl is wave-private: wave-local drain orders ds_write -> ds_read.
        asm volatile("s_waitcnt lgkmcnt(0)" ::: "memory");

        #pragma unroll
        for (int ks = 0; ks < 2; ++ks) {
            f16x8 pa0 = *(const f16x8*)&Pl[wid][( 0 + c) * 72 + ks * 32 + g * 8];
            f16x8 pa1 = *(const f16x8*)&Pl[wid][(16 + c) * 72 + ks * 32 + g * 8];
            #pragma unroll
            for (int dn = 0; dn < 4; ++dn) {
                f16x8 vb = *(const f16x8*)&Vl[(dn * 16 + c) * 72 + ks * 32 + g * 8];
                o[0][dn] = MFMA16(pa0, vb, o[0][dn]);
                o[1][dn] = MFMA16(pa1, vb, o[1][dn]);
            }
        }
    }

    // ---------------- dead tiles: QK^T + pre_score store only --------------
    for (int kt = live; kt < 32; ++kt) {
        __syncthreads();
        #pragma unroll
        for (int rr = 0; rr < 2; ++rr) {
            int row = sr + rr * 32;
            *(uint4*)&Kl[row * 72 + sc * 8] =
                *(const uint4*)&Kbase[(size_t)(kt * 64 + row) * 512 + sc * 8];
        }
        __syncthreads();

        f32x4 s[2][4] = {};
        #pragma unroll
        for (int nf = 0; nf < 4; ++nf)
            #pragma unroll
            for (int ks = 0; ks < 2; ++ks) {
                f16x8 kf = *(const f16x8*)&Kl[(nf * 16 + c) * 72 + ks * 32 + g * 8];
                s[0][nf] = MFMA16(qf[0][ks], kf, s[0][nf]);
                s[1][nf] = MFMA16(qf[1][ks], kf, s[1][nf]);
            }
        #pragma unroll
        for (int nf = 0; nf < 4; ++nf) {
            int tg = kt * 64 + nf * 16 + c;
            #pragma unroll
            for (int mi = 0; mi < 2; ++mi)
                #pragma unroll
                for (int r = 0; r < 4; ++r) {
                    int srow = q0 + mi * 16 + g * 4 + r;
                    __builtin_nontemporal_store(s[mi][nf][r] * 0.125f,
                        &pre_score[((size_t)n * 2048 + srow) * 2048 + tg]);
                }
        }
    }

    // ---- epilogue: O /= l (or uniform-row override), write heads f16 -----
    #pragma unroll
    for (int mi = 0; mi < 2; ++mi)
        #pragma unroll
        for (int r = 0; r < 4; ++r) {
            int srow = q0 + mi * 16 + g * 4 + r;
            bool dead = (mrow[mi][r] == MASKNEG);   // no valid key in whole row
            float inv_l = dead ? 0.f : 1.0f / lrow[mi][r];
            #pragma unroll
            for (int dn = 0; dn < 4; ++dn) {
                float val = dead ? Vsum[n * 64 + dn * 16 + c] * (1.0f / 2048.0f)
                                 : o[mi][dn][r] * inv_l;
                attn_out[(size_t)(b * 2048 + srow) * 512 + h * 64 + dn * 16 + c] = (f16)val;
            }
        }
}

// ---------------------------------------------------------------------------
// Kernel 3: output projection.  out[m,n] = sum_c heads[m,c]*Wo[n,c] + bo[n]
// ---------------------------------------------------------------------------
__global__ __launch_bounds__(256) void out_gemm(
    const f16* __restrict__ Aattn, const float* __restrict__ Wo,
    const float* __restrict__ bo, float* __restrict__ outp)
{
    __shared__ f16 Al[128 * 48];
    __shared__ f16 Wl[64 * 48];

    const int tid = threadIdx.x;
    const int n0 = blockIdx.x * 64;
    const int m0 = blockIdx.y * 128;
    const int wid = tid >> 6, lane = tid & 63;
    const int g = lane >> 4, c = lane & 15;
    const int wm = (wid >> 1) * 64, wn = (wid & 1) * 32;

    const int sr4 = tid >> 2, sc4 = tid & 3;   // A: 64 rows x 4 16B-chunks
    const int sr8 = tid >> 3, sc8 = tid & 7;   // W: 32 rows x 8 float4-chunks

    f32x4 acc[4][2] = {};

    for (int kk = 0; kk < 512; kk += 32) {
        __syncthreads();
        #pragma unroll
        for (int rr = 0; rr < 2; ++rr) {
            int row = sr4 + rr * 64;
            *(uint4*)&Al[row * 48 + sc4 * 8] =
                *(const uint4*)&Aattn[(size_t)(m0 + row) * 512 + kk + sc4 * 8];
        }
        #pragma unroll
        for (int rr = 0; rr < 2; ++rr) {
            int row = sr8 + rr * 32;
            float4 v = *(const float4*)&Wo[(size_t)(n0 + row) * 512 + kk + sc8 * 4];
            f16x4 h4 = {(f16)v.x, (f16)v.y, (f16)v.z, (f16)v.w};
            *(f16x4*)&Wl[row * 48 + sc8 * 4] = h4;
        }
        __syncthreads();

        f16x8 b0 = *(const f16x8*)&Wl[(wn +  0 + c) * 48 + g * 8];
        f16x8 b1 = *(const f16x8*)&Wl[(wn + 16 + c) * 48 + g * 8];
        #pragma unroll
        for (int mf = 0; mf < 4; ++mf) {
            f16x8 a = *(const f16x8*)&Al[(wm + mf * 16 + c) * 48 + g * 8];
            acc[mf][0] = MFMA16(a, b0, acc[mf][0]);
            acc[mf][1] = MFMA16(a, b1, acc[mf][1]);
        }
    }

    #pragma unroll
    for (int nf = 0; nf < 2; ++nf) {
        int cc = n0 + wn + nf * 16 + c;
        float bval = bo[cc];
        #pragma unroll
        for (int mf = 0; mf < 4; ++mf)
            #pragma unroll
            for (int r = 0; r < 4; ++r)
                outp[(size_t)(m0 + wm + mf * 16 + g * 4 + r) * 512 + cc] =
                    acc[mf][nf][r] + bval;
    }
}

// ---------------------------------------------------------------------------
extern "C" void kernel_launch(void* const* d_in, const int* in_sizes, int n_in,
                              void* d_out, int out_size, void* d_ws, size_t ws_size,
                              hipStream_t stream)
{
    (void)in_sizes; (void)n_in; (void)out_size; (void)ws_size;

    const float* x  = (const float*)d_in[0];
    const int*   pm = (const int*)  d_in[1];
    const float* Wq = (const float*)d_in[2];
    const float* bq = (const float*)d_in[3];
    const float* Wk = (const float*)d_in[4];
    const float* bk = (const float*)d_in[5];
    const float* Wv = (const float*)d_in[6];
    const float* bv = (const float*)d_in[7];
    const float* Wo = (const float*)d_in[8];
    const float* bo = (const float*)d_in[9];

    float* out = (float*)d_out;                 // [4][2048][512]
    float* pre = out + (size_t)4 * 2048 * 512;  // [32][2048][2048]

    f16*   Qws  = (f16*)d_ws;                   //  8 MiB
    f16*   Kws  = Qws + (size_t)8192 * 512;     //  8 MiB
    f16*   Vt   = Kws + (size_t)8192 * 512;     //  8 MiB (transposed V)
    f16*   Aat  = Vt  + (size_t)2048 * 2048;    //  8 MiB (heads)
    float* Vsum = (float*)(Aat + (size_t)8192 * 512);  // 8 KiB

    qkv_gemm   <<<dim3(24, 64), 256, 0, stream>>>(x, Wq, bq, Wk, bk, Wv, bv, Qws, Kws, Vt);
    vsum_kernel<<<dim3(512),    256, 0, stream>>>(Vt, Vsum);
    attn_kernel<<<dim3(16, 32), 256, 0, stream>>>(Qws, Kws, Vt, pm, Vsum, pre, Aat);
    out_gemm   <<<dim3(8, 64),  256, 0, stream>>>(Aat, Wo, bo, out);
}

// Round 4
// 308.395 us; speedup vs baseline: 1.0929x; 1.0929x over previous
//
#include <hip/hip_runtime.h>
#include <hip/hip_fp16.h>
#include <math.h>

typedef _Float16 f16;
typedef _Float16 f16x8 __attribute__((ext_vector_type(8)));
typedef _Float16 f16x4 __attribute__((ext_vector_type(4)));
typedef float    f32x4 __attribute__((ext_vector_type(4)));

#define MFMA16(a,b,c) __builtin_amdgcn_mfma_f32_16x16x32_f16(a, b, c, 0, 0, 0)

// log2-domain masked-fill sentinel; exp2(MASKNEG - m_real) underflows to 0,
// and a row whose max stays MASKNEG is "fully masked" -> uniform-softmax
// override in the epilogue (matches the reference's finite -2^32 fill).
#define MASKNEG (-6.0e9f)
#define LOG2E   1.44269504088896f

// ---------------------------------------------------------------------------
// Kernel 1: QKV projection.  out[m,c] = sum_k x[m,k] * W[c,k] + b[c]
// Q,K natural f16 [8192][512]; V transposed f16 [(h*4+b)*64+d][2048].
// ---------------------------------------------------------------------------
__global__ __launch_bounds__(256) void qkv_gemm(
    const float* __restrict__ x,
    const float* __restrict__ Wq, const float* __restrict__ bq,
    const float* __restrict__ Wk, const float* __restrict__ bk,
    const float* __restrict__ Wv, const float* __restrict__ bv,
    f16* __restrict__ Qws, f16* __restrict__ Kws, f16* __restrict__ Vt)
{
    __shared__ f16 Al[128 * 48];   // stride 48 f16 = 96B (16B aligned rows)
    __shared__ f16 Wl[64 * 48];

    const int tid = threadIdx.x;
    const int bx  = blockIdx.x;          // 0..23 (3 weights x 8 n-tiles)
    const int m0  = blockIdx.y * 128;
    const int widx = bx >> 3;            // 0=Q 1=K 2=V
    const int n0   = (bx & 7) * 64;

    const float* W    = (widx == 0) ? Wq : (widx == 1) ? Wk : Wv;
    const float* bias = (widx == 0) ? bq : (widx == 1) ? bk : bv;

    const int wid = tid >> 6, lane = tid & 63;
    const int g = lane >> 4, c = lane & 15;
    const int wm = (wid >> 1) * 64, wn = (wid & 1) * 32;

    const int sr = tid >> 3, sc = tid & 7;   // staging: 32 rows x 8 float4-chunks

    f32x4 acc[4][2] = {};

    for (int kk = 0; kk < 512; kk += 32) {
        __syncthreads();
        #pragma unroll
        for (int rr = 0; rr < 4; ++rr) {            // A: 128 rows x 32 k
            int row = sr + rr * 32;
            float4 v = *(const float4*)&x[(size_t)(m0 + row) * 512 + kk + sc * 4];
            f16x4 h4 = {(f16)v.x, (f16)v.y, (f16)v.z, (f16)v.w};
            *(f16x4*)&Al[row * 48 + sc * 4] = h4;
        }
        #pragma unroll
        for (int rr = 0; rr < 2; ++rr) {            // W: 64 rows x 32 k
            int row = sr + rr * 32;
            float4 v = *(const float4*)&W[(size_t)(n0 + row) * 512 + kk + sc * 4];
            f16x4 h4 = {(f16)v.x, (f16)v.y, (f16)v.z, (f16)v.w};
            *(f16x4*)&Wl[row * 48 + sc * 4] = h4;
        }
        __syncthreads();

        f16x8 b0 = *(const f16x8*)&Wl[(wn +  0 + c) * 48 + g * 8];
        f16x8 b1 = *(const f16x8*)&Wl[(wn + 16 + c) * 48 + g * 8];
        #pragma unroll
        for (int mf = 0; mf < 4; ++mf) {
            f16x8 a = *(const f16x8*)&Al[(wm + mf * 16 + c) * 48 + g * 8];
            acc[mf][0] = MFMA16(a, b0, acc[mf][0]);
            acc[mf][1] = MFMA16(a, b1, acc[mf][1]);
        }
    }

    #pragma unroll
    for (int nf = 0; nf < 2; ++nf) {
        int cc = n0 + wn + nf * 16 + c;
        float bval = bias[cc];
        #pragma unroll
        for (int mf = 0; mf < 4; ++mf) {
            if (widx < 2) {
                f16* outp = (widx == 0) ? Qws : Kws;
                #pragma unroll
                for (int r = 0; r < 4; ++r) {
                    int mrow = m0 + wm + mf * 16 + g * 4 + r;
                    outp[(size_t)mrow * 512 + cc] = (f16)(acc[mf][nf][r] + bval);
                }
            } else {
                int h  = n0 >> 6;
                int d  = wn + nf * 16 + c;
                int t0 = m0 + wm + mf * 16 + g * 4;
                int b  = t0 >> 11;
                int ts = t0 & 2047;
                int nn = h * 4 + b;
                f16x4 pk = {(f16)(acc[mf][nf][0] + bval), (f16)(acc[mf][nf][1] + bval),
                            (f16)(acc[mf][nf][2] + bval), (f16)(acc[mf][nf][3] + bval)};
                *(f16x4*)&Vt[((size_t)(nn * 64 + d)) * 2048 + ts] = pk;
            }
        }
    }
}

// ---------------------------------------------------------------------------
// Kernel 1b: per-(n,d) sum of V over t, for the fully-masked-row override.
// ---------------------------------------------------------------------------
__global__ __launch_bounds__(256) void vsum_kernel(
    const f16* __restrict__ Vt, float* __restrict__ Vsum)
{
    const int row  = blockIdx.x * 4 + (threadIdx.x >> 6);
    const int lane = threadIdx.x & 63;
    const f16* p = Vt + (size_t)row * 2048;
    float s = 0.f;
    #pragma unroll
    for (int i = 0; i < 4; ++i) {
        f16x8 v = *(const f16x8*)&p[i * 512 + lane * 8];
        #pragma unroll
        for (int j = 0; j < 8; ++j) s += (float)v[j];
    }
    #pragma unroll
    for (int off = 1; off < 64; off <<= 1) s += __shfl_xor(s, off, 64);
    if (lane == 0) Vsum[row] = s;
}

// ---------------------------------------------------------------------------
// Kernel 2: fused attention with WORK-BALANCED causal skip.
// Block (qt, n): owns 64-row chunk qt (low) and chunk 31-qt (high).
// Per wave: mi=0 -> 16 low rows, mi=1 -> 16 high rows.
//   phase A  kt in [0,qt]      : both chunks full body        (qt+1 tiles)
//   phase B  kt in (qt,31-qt]  : high full, low score-only    (31-2qt tiles)
//   phase C  kt in (31-qt,32)  : score-only, barrier-free, K direct from L2
// Full-body sub-tiles per block = 2(qt+1)+(31-2qt) = 33, uniform -> balanced
// makespan (all 512 blocks are co-resident; duration = slowest block).
// ---------------------------------------------------------------------------
__global__ __launch_bounds__(256) void attn_kernel(
    const f16* __restrict__ Qws, const f16* __restrict__ Kws,
    const f16* __restrict__ Vt,  const int* __restrict__ pmask,
    const float* __restrict__ Vsum,
    float* __restrict__ pre_score, f16* __restrict__ attn_out)
{
    __shared__ f16 Kl[64 * 72];        // [t][d], stride 72 f16 = 144B
    __shared__ f16 Vl[64 * 72];        // [d][t]
    __shared__ f16 Pl[4][32 * 72];     // per-wave [q][t]; rows mi*16..mi*16+15

    const int tid = threadIdx.x;
    const int wid = tid >> 6, lane = tid & 63;
    const int g = lane >> 4, c = lane & 15;
    const int qt = blockIdx.x;         // 0..15
    const int n  = blockIdx.y;         // 0..31  (= h*4 + b)
    const int h = n >> 2, b = n & 3;
    const int pmrow = n >> 3;          // the reference's ordering quirk
    const int qlo = qt * 64 + wid * 16;
    const int qhi = (31 - qt) * 64 + wid * 16;

    // Q fragments (A-op: lane -> Q[q=c, k=ks*32+g*8+j])
    f16x8 qf[2][2];
    #pragma unroll
    for (int ks = 0; ks < 2; ++ks) {
        qf[0][ks] = *(const f16x8*)
            &Qws[(size_t)(b * 2048 + qlo + c) * 512 + h * 64 + ks * 32 + g * 8];
        qf[1][ks] = *(const f16x8*)
            &Qws[(size_t)(b * 2048 + qhi + c) * 512 + h * 64 + ks * 32 + g * 8];
    }

    f32x4 o[2][4] = {};
    float mrow[2][4], lrow[2][4];
    #pragma unroll
    for (int mi = 0; mi < 2; ++mi)
        #pragma unroll
        for (int r = 0; r < 4; ++r) { mrow[mi][r] = -INFINITY; lrow[mi][r] = 0.0f; }

    const int sr = tid >> 3, sc = tid & 7;
    const int* pmp = pmask + pmrow * 2048;
    const f16* Kbase = Kws + (size_t)(b * 2048) * 512 + h * 64;
    const f16* Vbase = Vt + (size_t)(n * 64) * 2048;
    float* prow0 = pre_score + ((size_t)n * 2048 + qlo + g * 4) * 2048;
    float* prow1 = pre_score + ((size_t)n * 2048 + qhi + g * 4) * 2048;

    // Full tile body; L0/L1 are call-site literals -> folded branches.
    auto tile = [&](int kt, bool L0, bool L1) __attribute__((always_inline)) {
        __syncthreads();
        #pragma unroll
        for (int rr = 0; rr < 2; ++rr) {
            int row = sr + rr * 32;
            *(uint4*)&Kl[row * 72 + sc * 8] =
                *(const uint4*)&Kbase[(size_t)(kt * 64 + row) * 512 + sc * 8];
            *(uint4*)&Vl[row * 72 + sc * 8] =
                *(const uint4*)&Vbase[(size_t)row * 2048 + kt * 64 + sc * 8];
        }
        __syncthreads();

        f32x4 s[2][4] = {};
        #pragma unroll
        for (int nf = 0; nf < 4; ++nf)
            #pragma unroll
            for (int ks = 0; ks < 2; ++ks) {
                f16x8 kf = *(const f16x8*)&Kl[(nf * 16 + c) * 72 + ks * 32 + g * 8];
                s[0][nf] = MFMA16(qf[0][ks], kf, s[0][nf]);
                s[1][nf] = MFMA16(qf[1][ks], kf, s[1][nf]);
            }

        // emit pre_score for BOTH chunks; mask+log2 in-place for live chunks
        #pragma unroll
        for (int nf = 0; nf < 4; ++nf) {
            int tg  = kt * 64 + nf * 16 + c;
            int pmv = pmp[tg];
            #pragma unroll
            for (int r = 0; r < 4; ++r) {
                float v0 = s[0][nf][r] * 0.125f;
                float v1 = s[1][nf][r] * 0.125f;
                __builtin_nontemporal_store(v0, &prow0[(size_t)r * 2048 + tg]);
                __builtin_nontemporal_store(v1, &prow1[(size_t)r * 2048 + tg]);
                if (L0) s[0][nf][r] = (tg <= qlo + g * 4 + r && pmv != 0)
                                    ? v0 * LOG2E : MASKNEG;
                if (L1) s[1][nf][r] = (tg <= qhi + g * 4 + r && pmv != 0)
                                    ? v1 * LOG2E : MASKNEG;
            }
        }

        // online softmax (log2 domain) per live chunk
        #pragma unroll
        for (int mi = 0; mi < 2; ++mi) {
            if (mi == 0 && !L0) continue;
            if (mi == 1 && !L1) continue;
            float alpha[4];
            #pragma unroll
            for (int r = 0; r < 4; ++r) {
                float rm = fmaxf(fmaxf(s[mi][0][r], s[mi][1][r]),
                                 fmaxf(s[mi][2][r], s[mi][3][r]));
                rm = fmaxf(rm, __shfl_xor(rm, 1, 64));
                rm = fmaxf(rm, __shfl_xor(rm, 2, 64));
                rm = fmaxf(rm, __shfl_xor(rm, 4, 64));
                rm = fmaxf(rm, __shfl_xor(rm, 8, 64));
                float mn = fmaxf(mrow[mi][r], rm);
                alpha[r] = exp2f(mrow[mi][r] - mn);
                mrow[mi][r] = mn;
            }
            float rs[4] = {0.f, 0.f, 0.f, 0.f};
            #pragma unroll
            for (int nf = 0; nf < 4; ++nf)
                #pragma unroll
                for (int r = 0; r < 4; ++r) {
                    float p = exp2f(s[mi][nf][r] - mrow[mi][r]);
                    rs[r] += p;
                    Pl[wid][(mi * 16 + g * 4 + r) * 72 + nf * 16 + c] = (f16)p;
                }
            #pragma unroll
            for (int r = 0; r < 4; ++r) {
                float t = rs[r];
                t += __shfl_xor(t, 1, 64);
                t += __shfl_xor(t, 2, 64);
                t += __shfl_xor(t, 4, 64);
                t += __shfl_xor(t, 8, 64);
                lrow[mi][r] = lrow[mi][r] * alpha[r] + t;
                #pragma unroll
                for (int dn = 0; dn < 4; ++dn) o[mi][dn][r] *= alpha[r];
            }
        }
        // Pl is wave-private: wave-local drain orders ds_write -> ds_read.
        asm volatile("s_waitcnt lgkmcnt(0)" ::: "memory");

        #pragma unroll
        for (int ks = 0; ks < 2; ++ks) {
            f16x8 pa0, pa1;
            if (L0) pa0 = *(const f16x8*)&Pl[wid][( 0 + c) * 72 + ks * 32 + g * 8];
            if (L1) pa1 = *(const f16x8*)&Pl[wid][(16 + c) * 72 + ks * 32 + g * 8];
            #pragma unroll
            for (int dn = 0; dn < 4; ++dn) {
                f16x8 vb = *(const f16x8*)&Vl[(dn * 16 + c) * 72 + ks * 32 + g * 8];
                if (L0) o[0][dn] = MFMA16(pa0, vb, o[0][dn]);
                if (L1) o[1][dn] = MFMA16(pa1, vb, o[1][dn]);
            }
        }
    };

    for (int kt = 0; kt <= qt; ++kt)          tile(kt, true,  true);
    for (int kt = qt + 1; kt <= 31 - qt; ++kt) tile(kt, false, true);

    // phase C: score-only, barrier-free, K fragments direct from global (L2)
    for (int kt = 32 - qt; kt < 32; ++kt) {
        f32x4 s[2][4] = {};
        #pragma unroll
        for (int nf = 0; nf < 4; ++nf)
            #pragma unroll
            for (int ks = 0; ks < 2; ++ks) {
                f16x8 kf = *(const f16x8*)
                    &Kbase[(size_t)(kt * 64 + nf * 16 + c) * 512 + ks * 32 + g * 8];
                s[0][nf] = MFMA16(qf[0][ks], kf, s[0][nf]);
                s[1][nf] = MFMA16(qf[1][ks], kf, s[1][nf]);
            }
        #pragma unroll
        for (int nf = 0; nf < 4; ++nf) {
            int tg = kt * 64 + nf * 16 + c;
            #pragma unroll
            for (int r = 0; r < 4; ++r) {
                __builtin_nontemporal_store(s[0][nf][r] * 0.125f,
                                            &prow0[(size_t)r * 2048 + tg]);
                __builtin_nontemporal_store(s[1][nf][r] * 0.125f,
                                            &prow1[(size_t)r * 2048 + tg]);
            }
        }
    }

    // ---- epilogue: O /= l (or uniform-row override), write heads f16 -----
    #pragma unroll
    for (int mi = 0; mi < 2; ++mi) {
        int qb = mi ? qhi : qlo;
        #pragma unroll
        for (int r = 0; r < 4; ++r) {
            int srow = qb + g * 4 + r;
            bool dead = (mrow[mi][r] == MASKNEG);   // no valid key in whole row
            float inv_l = dead ? 0.f : 1.0f / lrow[mi][r];
            #pragma unroll
            for (int dn = 0; dn < 4; ++dn) {
                float val = dead ? Vsum[n * 64 + dn * 16 + c] * (1.0f / 2048.0f)
                                 : o[mi][dn][r] * inv_l;
                attn_out[(size_t)(b * 2048 + srow) * 512 + h * 64 + dn * 16 + c] = (f16)val;
            }
        }
    }
}

// ---------------------------------------------------------------------------
// Kernel 3: output projection.  out[m,n] = sum_c heads[m,c]*Wo[n,c] + bo[n]
// ---------------------------------------------------------------------------
__global__ __launch_bounds__(256) void out_gemm(
    const f16* __restrict__ Aattn, const float* __restrict__ Wo,
    const float* __restrict__ bo, float* __restrict__ outp)
{
    __shared__ f16 Al[128 * 48];
    __shared__ f16 Wl[64 * 48];

    const int tid = threadIdx.x;
    const int n0 = blockIdx.x * 64;
    const int m0 = blockIdx.y * 128;
    const int wid = tid >> 6, lane = tid & 63;
    const int g = lane >> 4, c = lane & 15;
    const int wm = (wid >> 1) * 64, wn = (wid & 1) * 32;

    const int sr4 = tid >> 2, sc4 = tid & 3;
    const int sr8 = tid >> 3, sc8 = tid & 7;

    f32x4 acc[4][2] = {};

    for (int kk = 0; kk < 512; kk += 32) {
        __syncthreads();
        #pragma unroll
        for (int rr = 0; rr < 2; ++rr) {
            int row = sr4 + rr * 64;
            *(uint4*)&Al[row * 48 + sc4 * 8] =
                *(const uint4*)&Aattn[(size_t)(m0 + row) * 512 + kk + sc4 * 8];
        }
        #pragma unroll
        for (int rr = 0; rr < 2; ++rr) {
            int row = sr8 + rr * 32;
            float4 v = *(const float4*)&Wo[(size_t)(n0 + row) * 512 + kk + sc8 * 4];
            f16x4 h4 = {(f16)v.x, (f16)v.y, (f16)v.z, (f16)v.w};
            *(f16x4*)&Wl[row * 48 + sc8 * 4] = h4;
        }
        __syncthreads();

        f16x8 b0 = *(const f16x8*)&Wl[(wn +  0 + c) * 48 + g * 8];
        f16x8 b1 = *(const f16x8*)&Wl[(wn + 16 + c) * 48 + g * 8];
        #pragma unroll
        for (int mf = 0; mf < 4; ++mf) {
            f16x8 a = *(const f16x8*)&Al[(wm + mf * 16 + c) * 48 + g * 8];
            acc[mf][0] = MFMA16(a, b0, acc[mf][0]);
            acc[mf][1] = MFMA16(a, b1, acc[mf][1]);
        }
    }

    #pragma unroll
    for (int nf = 0; nf < 2; ++nf) {
        int cc = n0 + wn + nf * 16 + c;
        float bval = bo[cc];
        #pragma unroll
        for (int mf = 0; mf < 4; ++mf)
            #pragma unroll
            for (int r = 0; r < 4; ++r)
                outp[(size_t)(m0 + wm + mf * 16 + g * 4 + r) * 512 + cc] =
                    acc[mf][nf][r] + bval;
    }
}

// ---------------------------------------------------------------------------
extern "C" void kernel_launch(void* const* d_in, const int* in_sizes, int n_in,
                              void* d_out, int out_size, void* d_ws, size_t ws_size,
                              hipStream_t stream)
{
    (void)in_sizes; (void)n_in; (void)out_size; (void)ws_size;

    const float* x  = (const float*)d_in[0];
    const int*   pm = (const int*)  d_in[1];
    const float* Wq = (const float*)d_in[2];
    const float* bq = (const float*)d_in[3];
    const float* Wk = (const float*)d_in[4];
    const float* bk = (const float*)d_in[5];
    const float* Wv = (const float*)d_in[6];
    const float* bv = (const float*)d_in[7];
    const float* Wo = (const float*)d_in[8];
    const float* bo = (const float*)d_in[9];

    float* out = (float*)d_out;                 // [4][2048][512]
    float* pre = out + (size_t)4 * 2048 * 512;  // [32][2048][2048]

    f16*   Qws  = (f16*)d_ws;                   //  8 MiB
    f16*   Kws  = Qws + (size_t)8192 * 512;     //  8 MiB
    f16*   Vt   = Kws + (size_t)8192 * 512;     //  8 MiB (transposed V)
    f16*   Aat  = Vt  + (size_t)2048 * 2048;    //  8 MiB (heads)
    float* Vsum = (float*)(Aat + (size_t)8192 * 512);  // 8 KiB

    qkv_gemm   <<<dim3(24, 64), 256, 0, stream>>>(x, Wq, bq, Wk, bk, Wv, bv, Qws, Kws, Vt);
    vsum_kernel<<<dim3(512),    256, 0, stream>>>(Vt, Vsum);
    attn_kernel<<<dim3(16, 32), 256, 0, stream>>>(Qws, Kws, Vt, pm, Vsum, pre, Aat);
    out_gemm   <<<dim3(8, 64),  256, 0, stream>>>(Aat, Wo, bo, out);
}

// Round 5
// 286.004 us; speedup vs baseline: 1.1784x; 1.0783x over previous
//
#include <hip/hip_runtime.h>
#include <hip/hip_fp16.h>
#include <math.h>

typedef _Float16 f16;
typedef _Float16 f16x8 __attribute__((ext_vector_type(8)));
typedef _Float16 f16x4 __attribute__((ext_vector_type(4)));
typedef float    f32x4 __attribute__((ext_vector_type(4)));

#define MFMA16(a,b,c) __builtin_amdgcn_mfma_f32_16x16x32_f16(a, b, c, 0, 0, 0)

#define MASKNEG (-6.0e9f)     // additive mask fill (score units)
#define DEADTHR (-1.0e9f)     // row-max below this => fully-masked row
#define LOG2E   1.44269504088896f

// ---------------------------------------------------------------------------
// Kernel 1: QKV projection.  Q is PRE-SCALED by 1/8 (softmax scale folded).
// Q,K natural f16 [8192][512]; V transposed f16 [(h*4+b)*64+d][2048].
// ---------------------------------------------------------------------------
__global__ __launch_bounds__(256) void qkv_gemm(
    const float* __restrict__ x,
    const float* __restrict__ Wq, const float* __restrict__ bq,
    const float* __restrict__ Wk, const float* __restrict__ bk,
    const float* __restrict__ Wv, const float* __restrict__ bv,
    f16* __restrict__ Qws, f16* __restrict__ Kws, f16* __restrict__ Vt)
{
    __shared__ f16 Al[128 * 48];
    __shared__ f16 Wl[64 * 48];

    const int tid = threadIdx.x;
    const int bx  = blockIdx.x;          // 0..23 (3 weights x 8 n-tiles)
    const int m0  = blockIdx.y * 128;
    const int widx = bx >> 3;            // 0=Q 1=K 2=V
    const int n0   = (bx & 7) * 64;

    const float* W    = (widx == 0) ? Wq : (widx == 1) ? Wk : Wv;
    const float* bias = (widx == 0) ? bq : (widx == 1) ? bk : bv;
    const float scl  = (widx == 0) ? 0.125f : 1.0f;

    const int wid = tid >> 6, lane = tid & 63;
    const int g = lane >> 4, c = lane & 15;
    const int wm = (wid >> 1) * 64, wn = (wid & 1) * 32;
    const int sr = tid >> 3, sc = tid & 7;

    f32x4 acc[4][2] = {};

    for (int kk = 0; kk < 512; kk += 32) {
        __syncthreads();
        #pragma unroll
        for (int rr = 0; rr < 4; ++rr) {
            int row = sr + rr * 32;
            float4 v = *(const float4*)&x[(size_t)(m0 + row) * 512 + kk + sc * 4];
            f16x4 h4 = {(f16)v.x, (f16)v.y, (f16)v.z, (f16)v.w};
            *(f16x4*)&Al[row * 48 + sc * 4] = h4;
        }
        #pragma unroll
        for (int rr = 0; rr < 2; ++rr) {
            int row = sr + rr * 32;
            float4 v = *(const float4*)&W[(size_t)(n0 + row) * 512 + kk + sc * 4];
            f16x4 h4 = {(f16)v.x, (f16)v.y, (f16)v.z, (f16)v.w};
            *(f16x4*)&Wl[row * 48 + sc * 4] = h4;
        }
        __syncthreads();

        f16x8 b0 = *(const f16x8*)&Wl[(wn +  0 + c) * 48 + g * 8];
        f16x8 b1 = *(const f16x8*)&Wl[(wn + 16 + c) * 48 + g * 8];
        #pragma unroll
        for (int mf = 0; mf < 4; ++mf) {
            f16x8 a = *(const f16x8*)&Al[(wm + mf * 16 + c) * 48 + g * 8];
            acc[mf][0] = MFMA16(a, b0, acc[mf][0]);
            acc[mf][1] = MFMA16(a, b1, acc[mf][1]);
        }
    }

    #pragma unroll
    for (int nf = 0; nf < 2; ++nf) {
        int cc = n0 + wn + nf * 16 + c;
        float bval = bias[cc];
        #pragma unroll
        for (int mf = 0; mf < 4; ++mf) {
            if (widx < 2) {
                f16* outp = (widx == 0) ? Qws : Kws;
                #pragma unroll
                for (int r = 0; r < 4; ++r) {
                    int mrow = m0 + wm + mf * 16 + g * 4 + r;
                    outp[(size_t)mrow * 512 + cc] = (f16)((acc[mf][nf][r] + bval) * scl);
                }
            } else {
                int h  = n0 >> 6;
                int d  = wn + nf * 16 + c;
                int t0 = m0 + wm + mf * 16 + g * 4;
                int b  = t0 >> 11;
                int ts = t0 & 2047;
                int nn = h * 4 + b;
                f16x4 pk = {(f16)(acc[mf][nf][0] + bval), (f16)(acc[mf][nf][1] + bval),
                            (f16)(acc[mf][nf][2] + bval), (f16)(acc[mf][nf][3] + bval)};
                *(f16x4*)&Vt[((size_t)(nn * 64 + d)) * 2048 + ts] = pk;
            }
        }
    }
}

// ---------------------------------------------------------------------------
// Kernel 1b: per-(n,d) sum of V over t, for the fully-masked-row override.
// ---------------------------------------------------------------------------
__global__ __launch_bounds__(256) void vsum_kernel(
    const f16* __restrict__ Vt, float* __restrict__ Vsum)
{
    const int row  = blockIdx.x * 4 + (threadIdx.x >> 6);
    const int lane = threadIdx.x & 63;
    const f16* p = Vt + (size_t)row * 2048;
    float s = 0.f;
    #pragma unroll
    for (int i = 0; i < 4; ++i) {
        f16x8 v = *(const f16x8*)&p[i * 512 + lane * 8];
        #pragma unroll
        for (int j = 0; j < 8; ++j) s += (float)v[j];
    }
    #pragma unroll
    for (int off = 1; off < 64; off <<= 1) s += __shfl_xor(s, off, 64);
    if (lane == 0) Vsum[row] = s;
}

// ---------------------------------------------------------------------------
// Kernel 2: fused attention, swapped-QK^T, store-decoupled.
// Block (qt,n): chunk pair (qt, 31-qt), 64 rows each; wave owns 16 rows of
// each chunk (mi=0 low / mi=1 high).  Staged tiles kt in [0, 32-qt):
//   raw s_barrier + lgkmcnt only (NO vmcnt drain -> pre_score stores overlap);
//   next-tile K/V global loads issued BEFORE this tile's stores (in-order
//   vmcnt retirement then never waits on stores).
// S computed as mfma(K,Q): lane holds (row k = kc*16+g*4+reg, col q = c) ->
//   dwordx4 pre_score stores + lane-local softmax (2 shfls per reduce).
// Dead tiles kt in [32-qt, 32): barrier-free, K direct from L2/L3, score-only.
// ---------------------------------------------------------------------------
__global__ __launch_bounds__(256) void attn_kernel(
    const f16* __restrict__ Qws, const f16* __restrict__ Kws,
    const f16* __restrict__ Vt,  const int* __restrict__ pmask,
    const float* __restrict__ Vsum,
    float* __restrict__ pre_score, f16* __restrict__ attn_out)
{
    __shared__ f16 Kl[64 * 72];        // [t][d]
    __shared__ f16 Vl[64 * 72];        // [d][t]
    __shared__ f16 Pl[4][32 * 72];     // per-wave [q][k]
    __shared__ float Bias[2048];       // additive padding-mask bias

    const int tid = threadIdx.x;
    const int wid = tid >> 6, lane = tid & 63;
    const int g = lane >> 4, c = lane & 15;
    const int qt = blockIdx.x;         // 0..15
    const int n  = blockIdx.y;         // 0..31  (= h*4 + b)
    const int h = n >> 2, b = n & 3;
    const int pmrow = n >> 3;          // the reference's ordering quirk
    const int qlo = qt * 64 + wid * 16;
    const int qhi = (31 - qt) * 64 + wid * 16;
    const int qrel = wid * 16 + c;     // in-tile causal threshold (both chunks)

    // --- padding mask -> additive bias in LDS (removes vmem from softmax) ---
    {
        const int i0 = tid * 8;
        const int4* p4 = (const int4*)(pmask + pmrow * 2048 + i0);
        int4 m0 = p4[0], m1 = p4[1];
        Bias[i0 + 0] = m0.x ? 0.f : MASKNEG;
        Bias[i0 + 1] = m0.y ? 0.f : MASKNEG;
        Bias[i0 + 2] = m0.z ? 0.f : MASKNEG;
        Bias[i0 + 3] = m0.w ? 0.f : MASKNEG;
        Bias[i0 + 4] = m1.x ? 0.f : MASKNEG;
        Bias[i0 + 5] = m1.y ? 0.f : MASKNEG;
        Bias[i0 + 6] = m1.z ? 0.f : MASKNEG;
        Bias[i0 + 7] = m1.w ? 0.f : MASKNEG;
    }

    // Q fragments (B-operand now: lane -> Q[q=c, k=ks*32+g*8+j]); pre-scaled.
    f16x8 qf[2][2];
    #pragma unroll
    for (int ks = 0; ks < 2; ++ks) {
        qf[0][ks] = *(const f16x8*)
            &Qws[(size_t)(b * 2048 + qlo + c) * 512 + h * 64 + ks * 32 + g * 8];
        qf[1][ks] = *(const f16x8*)
            &Qws[(size_t)(b * 2048 + qhi + c) * 512 + h * 64 + ks * 32 + g * 8];
    }

    f32x4 o[2][4] = {};
    float mrow[2] = {-INFINITY, -INFINITY};   // per-lane row state (q = c)
    float lrow[2] = {0.f, 0.f};

    const int sr = tid >> 3, sc = tid & 7;
    const f16* Kbase = Kws + (size_t)(b * 2048) * 512 + h * 64;
    const f16* Vbase = Vt + (size_t)(n * 64) * 2048;
    float* prow0 = pre_score + ((size_t)n * 2048 + qlo + c) * 2048;
    float* prow1 = pre_score + ((size_t)n * 2048 + qhi + c) * 2048;

    const int stageEnd = 32 - qt;      // staged (any-live) tiles

    uint4 ka0, ka1, va0, va1;          // T14 reg staging
    auto glbload = [&](int kt) {
        ka0 = *(const uint4*)&Kbase[(size_t)(kt * 64 + sr) * 512 + sc * 8];
        ka1 = *(const uint4*)&Kbase[(size_t)(kt * 64 + sr + 32) * 512 + sc * 8];
        va0 = *(const uint4*)&Vbase[(size_t)sr * 2048 + kt * 64 + sc * 8];
        va1 = *(const uint4*)&Vbase[(size_t)(sr + 32) * 2048 + kt * 64 + sc * 8];
    };

    glbload(0);
    for (int kt = 0; kt < stageEnd; ++kt) {
        // all waves done with previous tile's LDS (reads drained wave-locally)
        asm volatile("s_waitcnt lgkmcnt(0)" ::: "memory");
        __builtin_amdgcn_s_barrier();
        *(uint4*)&Kl[sr * 72 + sc * 8]        = ka0;
        *(uint4*)&Kl[(sr + 32) * 72 + sc * 8] = ka1;
        *(uint4*)&Vl[sr * 72 + sc * 8]        = va0;
        *(uint4*)&Vl[(sr + 32) * 72 + sc * 8] = va1;
        asm volatile("s_waitcnt lgkmcnt(0)" ::: "memory");
        __builtin_amdgcn_s_barrier();
        if (kt + 1 < stageEnd) glbload(kt + 1);   // BEFORE stores

        // ---- S = K Q^T (swapped): lane (g,c) -> k=kc*16+g*4+r, q=c --------
        f32x4 s2[2][4] = {};
        #pragma unroll
        for (int kc = 0; kc < 4; ++kc)
            #pragma unroll
            for (int ks = 0; ks < 2; ++ks) {
                f16x8 kf = *(const f16x8*)&Kl[(kc * 16 + c) * 72 + ks * 32 + g * 8];
                s2[0][kc] = MFMA16(kf, qf[0][ks], s2[0][kc]);
                s2[1][kc] = MFMA16(kf, qf[1][ks], s2[1][kc]);
            }

        // ---- pre_score stores: one dwordx4 per (mi,kc) --------------------
        #pragma unroll
        for (int kc = 0; kc < 4; ++kc) {
            *(f32x4*)&prow0[kt * 64 + kc * 16 + g * 4] = s2[0][kc];
            *(f32x4*)&prow1[kt * 64 + kc * 16 + g * 4] = s2[1][kc];
        }

        // ---- bias (broadcast LDS read, shared by both chunks) -------------
        f32x4 bi[4];
        #pragma unroll
        for (int kc = 0; kc < 4; ++kc)
            bi[kc] = *(const f32x4*)&Bias[kt * 64 + kc * 16 + g * 4];

        const bool L0 = (kt <= qt);
        const bool bnd0 = (kt == qt), bnd1 = (kt == 31 - qt);

        // ---- per-chunk softmax (lane-local rows) + Pl + PV ----------------
        #pragma unroll
        for (int mi = 0; mi < 2; ++mi) {
            if (mi == 0 && !L0) continue;
            const bool bnd = mi ? bnd1 : bnd0;
            float sl[4][4];
            #pragma unroll
            for (int kc = 0; kc < 4; ++kc)
                #pragma unroll
                for (int r = 0; r < 4; ++r) {
                    float sv = s2[mi][kc][r] + bi[kc][r];
                    int klocal = kc * 16 + g * 4 + r;
                    sl[kc][r] = (bnd && klocal > qrel) ? MASKNEG : sv;
                }
            float rm = sl[0][0];
            #pragma unroll
            for (int kc = 0; kc < 4; ++kc)
                #pragma unroll
                for (int r = 0; r < 4; ++r) rm = fmaxf(rm, sl[kc][r]);
            rm = fmaxf(rm, __shfl_xor(rm, 16, 64));
            rm = fmaxf(rm, __shfl_xor(rm, 32, 64));
            float mn = fmaxf(mrow[mi], rm);
            float alpha = exp2f((mrow[mi] - mn) * LOG2E);
            mrow[mi] = mn;
            float ml2 = mn * LOG2E;
            float rs = 0.f;
            #pragma unroll
            for (int kc = 0; kc < 4; ++kc) {
                f16x4 pk;
                #pragma unroll
                for (int r = 0; r < 4; ++r) {
                    float p = exp2f(fmaf(sl[kc][r], LOG2E, -ml2));
                    rs += p;
                    pk[r] = (f16)p;
                }
                *(f16x4*)&Pl[wid][(mi * 16 + c) * 72 + kc * 16 + g * 4] = pk;
            }
            rs += __shfl_xor(rs, 16, 64);
            rs += __shfl_xor(rs, 32, 64);
            lrow[mi] = lrow[mi] * alpha + rs;
            // alpha lives at lanes by q=c; o rows are q=g*4+r -> transpose
            #pragma unroll
            for (int r = 0; r < 4; ++r) {
                float af = __shfl(alpha, g * 4 + r, 64);
                #pragma unroll
                for (int dn = 0; dn < 4; ++dn) o[mi][dn][r] *= af;
            }
        }
        // Pl wave-private write->read ordering
        asm volatile("s_waitcnt lgkmcnt(0)" ::: "memory");

        #pragma unroll
        for (int ks = 0; ks < 2; ++ks) {
            f16x8 pa0, pa1;
            if (L0) pa0 = *(const f16x8*)&Pl[wid][( 0 + c) * 72 + ks * 32 + g * 8];
            pa1 = *(const f16x8*)&Pl[wid][(16 + c) * 72 + ks * 32 + g * 8];
            #pragma unroll
            for (int dn = 0; dn < 4; ++dn) {
                f16x8 vb = *(const f16x8*)&Vl[(dn * 16 + c) * 72 + ks * 32 + g * 8];
                if (L0) o[0][dn] = MFMA16(pa0, vb, o[0][dn]);
                o[1][dn] = MFMA16(pa1, vb, o[1][dn]);
            }
        }
    }

    // ---- dead tiles: barrier-free score-only, K direct from L2/L3 ---------
    for (int kt = stageEnd; kt < 32; ++kt) {
        f32x4 s2[2][4] = {};
        #pragma unroll
        for (int kc = 0; kc < 4; ++kc)
            #pragma unroll
            for (int ks = 0; ks < 2; ++ks) {
                f16x8 kf = *(const f16x8*)
                    &Kbase[(size_t)(kt * 64 + kc * 16 + c) * 512 + ks * 32 + g * 8];
                s2[0][kc] = MFMA16(kf, qf[0][ks], s2[0][kc]);
                s2[1][kc] = MFMA16(kf, qf[1][ks], s2[1][kc]);
            }
        #pragma unroll
        for (int kc = 0; kc < 4; ++kc) {
            *(f32x4*)&prow0[kt * 64 + kc * 16 + g * 4] = s2[0][kc];
            *(f32x4*)&prow1[kt * 64 + kc * 16 + g * 4] = s2[1][kc];
        }
    }

    // ---- epilogue: transpose l/m to o-layout, divide, write heads ---------
    #pragma unroll
    for (int mi = 0; mi < 2; ++mi) {
        int qb = mi ? qhi : qlo;
        #pragma unroll
        for (int r = 0; r < 4; ++r) {
            float lo = __shfl(lrow[mi], g * 4 + r, 64);
            float mo = __shfl(mrow[mi], g * 4 + r, 64);
            int srow = qb + g * 4 + r;
            bool dead = (mo < DEADTHR);
            float inv_l = dead ? 0.f : 1.0f / lo;
            #pragma unroll
            for (int dn = 0; dn < 4; ++dn) {
                float val = dead ? Vsum[n * 64 + dn * 16 + c] * (1.0f / 2048.0f)
                                 : o[mi][dn][r] * inv_l;
                attn_out[(size_t)(b * 2048 + srow) * 512 + h * 64 + dn * 16 + c] = (f16)val;
            }
        }
    }
}

// ---------------------------------------------------------------------------
// Kernel 3: output projection.
// ---------------------------------------------------------------------------
__global__ __launch_bounds__(256) void out_gemm(
    const f16* __restrict__ Aattn, const float* __restrict__ Wo,
    const float* __restrict__ bo, float* __restrict__ outp)
{
    __shared__ f16 Al[128 * 48];
    __shared__ f16 Wl[64 * 48];

    const int tid = threadIdx.x;
    const int n0 = blockIdx.x * 64;
    const int m0 = blockIdx.y * 128;
    const int wid = tid >> 6, lane = tid & 63;
    const int g = lane >> 4, c = lane & 15;
    const int wm = (wid >> 1) * 64, wn = (wid & 1) * 32;

    const int sr4 = tid >> 2, sc4 = tid & 3;
    const int sr8 = tid >> 3, sc8 = tid & 7;

    f32x4 acc[4][2] = {};

    for (int kk = 0; kk < 512; kk += 32) {
        __syncthreads();
        #pragma unroll
        for (int rr = 0; rr < 2; ++rr) {
            int row = sr4 + rr * 64;
            *(uint4*)&Al[row * 48 + sc4 * 8] =
                *(const uint4*)&Aattn[(size_t)(m0 + row) * 512 + kk + sc4 * 8];
        }
        #pragma unroll
        for (int rr = 0; rr < 2; ++rr) {
            int row = sr8 + rr * 32;
            float4 v = *(const float4*)&Wo[(size_t)(n0 + row) * 512 + kk + sc8 * 4];
            f16x4 h4 = {(f16)v.x, (f16)v.y, (f16)v.z, (f16)v.w};
            *(f16x4*)&Wl[row * 48 + sc8 * 4] = h4;
        }
        __syncthreads();

        f16x8 b0 = *(const f16x8*)&Wl[(wn +  0 + c) * 48 + g * 8];
        f16x8 b1 = *(const f16x8*)&Wl[(wn + 16 + c) * 48 + g * 8];
        #pragma unroll
        for (int mf = 0; mf < 4; ++mf) {
            f16x8 a = *(const f16x8*)&Al[(wm + mf * 16 + c) * 48 + g * 8];
            acc[mf][0] = MFMA16(a, b0, acc[mf][0]);
            acc[mf][1] = MFMA16(a, b1, acc[mf][1]);
        }
    }

    #pragma unroll
    for (int nf = 0; nf < 2; ++nf) {
        int cc = n0 + wn + nf * 16 + c;
        float bval = bo[cc];
        #pragma unroll
        for (int mf = 0; mf < 4; ++mf)
            #pragma unroll
            for (int r = 0; r < 4; ++r)
                outp[(size_t)(m0 + wm + mf * 16 + g * 4 + r) * 512 + cc] =
                    acc[mf][nf][r] + bval;
    }
}

// ---------------------------------------------------------------------------
extern "C" void kernel_launch(void* const* d_in, const int* in_sizes, int n_in,
                              void* d_out, int out_size, void* d_ws, size_t ws_size,
                              hipStream_t stream)
{
    (void)in_sizes; (void)n_in; (void)out_size; (void)ws_size;

    const float* x  = (const float*)d_in[0];
    const int*   pm = (const int*)  d_in[1];
    const float* Wq = (const float*)d_in[2];
    const float* bq = (const float*)d_in[3];
    const float* Wk = (const float*)d_in[4];
    const float* bk = (const float*)d_in[5];
    const float* Wv = (const float*)d_in[6];
    const float* bv = (const float*)d_in[7];
    const float* Wo = (const float*)d_in[8];
    const float* bo = (const float*)d_in[9];

    float* out = (float*)d_out;                 // [4][2048][512]
    float* pre = out + (size_t)4 * 2048 * 512;  // [32][2048][2048]

    f16*   Qws  = (f16*)d_ws;                   //  8 MiB (pre-scaled by 1/8)
    f16*   Kws  = Qws + (size_t)8192 * 512;     //  8 MiB
    f16*   Vt   = Kws + (size_t)8192 * 512;     //  8 MiB (transposed V)
    f16*   Aat  = Vt  + (size_t)2048 * 2048;    //  8 MiB (heads)
    float* Vsum = (float*)(Aat + (size_t)8192 * 512);  // 8 KiB

    qkv_gemm   <<<dim3(24, 64), 256, 0, stream>>>(x, Wq, bq, Wk, bk, Wv, bv, Qws, Kws, Vt);
    vsum_kernel<<<dim3(512),    256, 0, stream>>>(Vt, Vsum);
    attn_kernel<<<dim3(16, 32), 256, 0, stream>>>(Qws, Kws, Vt, pm, Vsum, pre, Aat);
    out_gemm   <<<dim3(8, 64),  256, 0, stream>>>(Aat, Wo, bo, out);
}